// Round 3
// baseline (301.964 us; speedup 1.0000x reference)
//
#include <hip/hip_runtime.h>

// B=16, T=1024, N=1024, D=256, WIN=64
// outputs (flat): R (B,T,2D) = [A@V, Q]   : 8388608 f32
//                 alignments (B,N,T) = A^T: 16777216 f32
//                 max_att (B,T)           : 16384 f32
//
// Out-of-window softmax entries are exactly 0.0f. One kernel, two block
// roles by blockIdx parity:
//   odd  blocks (1024): zero-fill the 960 non-window alignment rows per
//        batch, fully coalesced (one 4KB block-wide float4 store per row).
//   even blocks (1024): attention for 16 queries; alignment write shrinks
//        to the 64 window rows (4KB, full 64B lines, no amplification).
// 2048 blocks x 4 waves = 8192 waves -> full occupancy potential
// (R2 was 4096 waves -> <=50%, measured 32%: latency-bound).

#define BB 16
#define TT 1024
#define NN 1024
#define DD 256
#define WIN 64
#define TBLK 16   // queries per attention block

#define R_ELEMS   (16u*1024u*512u)        // 8388608
#define ALN_ELEMS (16u*1024u*1024u)       // 16777216

__global__ __launch_bounds__(256) void attn_fused(
    const float* __restrict__ Q, const float* __restrict__ K,
    const float* __restrict__ V, const int* __restrict__ prev_in,
    float* __restrict__ out)
{
    __shared__ float p_a[WIN][TBLK + 1];   // [j][t_local]  (stride 17)
    __shared__ float p_t[TBLK][WIN + 4];   // [t_local][j]  (float4-aligned rows)

    float* Rout   = out;
    float* aligns = out + R_ELEMS;
    float* maxatt = out + R_ELEMS + ALN_ELEMS;

    const int tid = threadIdx.x;

    if (blockIdx.x & 1) {
        // ---------------- zero-fill role ----------------
        // zb in [0,1024): 64 blocks per batch, 15 non-window rows each.
        const int zb    = blockIdx.x >> 1;
        const int b     = zb >> 6;
        const int chunk = zb & 63;
        const int prev  = prev_in[b];
        float4* base = (float4*)(aligns + (size_t)b * NN * TT);
        const float4 z = make_float4(0.f, 0.f, 0.f, 0.f);
        #pragma unroll
        for (int r = 0; r < 15; ++r) {
            int idx = chunk * 15 + r;            // 0..959: index among non-window rows
            int n   = idx < prev ? idx : idx + WIN;
            base[(size_t)n * (TT / 4) + tid] = z;  // 256 threads = 4KB contiguous
        }
        return;
    }

    // ---------------- attention role ----------------
    const int lane = tid & 63;
    const int w    = tid >> 6;                 // wave 0..3
    const int ab   = blockIdx.x >> 1;          // 0..1023
    const int b    = ab >> 6;                  // 64 attn blocks per batch
    const int t0   = (ab & 63) * TBLK;
    const int prev = prev_in[b];

    // Phase 1: QK^T. Wave w: queries t0+w*4+{0..3}; lane = window col j.
    const float*  qb = Q + ((size_t)b * TT + t0 + w * 4) * DD;
    const float4* K4 = (const float4*)(K + ((size_t)b * NN + prev + lane) * DD);

    float acc[4] = {0.f, 0.f, 0.f, 0.f};
    for (int d4 = 0; d4 < DD / 4; ++d4) {
        float4 k = K4[d4];
        #pragma unroll
        for (int t = 0; t < 4; ++t) {
            float4 q = ((const float4*)(qb + t * DD))[d4];   // wave-broadcast load
            acc[t] = fmaf(q.x, k.x, fmaf(q.y, k.y, fmaf(q.z, k.z, fmaf(q.w, k.w, acc[t]))));
        }
    }

    // Phase 2: softmax + argmax per query; stash p in LDS (both layouts).
    #pragma unroll
    for (int t = 0; t < 4; ++t) {
        float v = acc[t] * 0.0625f;            // 1/sqrt(256)

        float m = v;
        #pragma unroll
        for (int off = 32; off; off >>= 1) m = fmaxf(m, __shfl_xor(m, off));

        float e = expf(v - m);
        float s = e;
        #pragma unroll
        for (int off = 32; off; off >>= 1) s += __shfl_xor(s, off);

        float p = e / s;
        const int tt = w * 4 + t;
        p_a[lane][tt] = p;
        p_t[tt][lane] = p;

        // argmax over logits (== argmax over A), first-index tiebreak
        float av = v; int ai = lane;
        #pragma unroll
        for (int off = 32; off; off >>= 1) {
            float ov = __shfl_xor(av, off);
            int   oi = __shfl_xor(ai, off);
            if (ov > av || (ov == av && oi < ai)) { av = ov; ai = oi; }
        }
        if (lane == 0) maxatt[(size_t)b * TT + t0 + tt] = (float)(prev + ai);
    }
    __syncthreads();

    // Phase 3: window-row alignment strip only — 64 rows x 16 cols = 4KB,
    // one float4 store per thread, full 64B lines.
    {
        const int rsub = tid >> 2;             // 0..63: window row
        const int cg   = tid & 3;              // float4 column group
        float4 val;
        val.x = p_a[rsub][cg * 4 + 0];
        val.y = p_a[rsub][cg * 4 + 1];
        val.z = p_a[rsub][cg * 4 + 2];
        val.w = p_a[rsub][cg * 4 + 3];
        *(float4*)(aligns + (size_t)b * NN * TT
                   + (size_t)(prev + rsub) * TT + t0 + cg * 4) = val;
    }

    // Phase 4: PV + R write. Thread = (t_local, d-chunk).
    {
        const int tl  = tid >> 4;              // 0..15
        const int dc0 = tid & 15;
        const float4* V4 = (const float4*)(V + ((size_t)b * NN + prev) * DD);
        const float4* Q4 = (const float4*)(Q + ((size_t)b * TT + t0 + tl) * DD);
        float4* R4 = (float4*)(Rout + ((size_t)b * TT + t0 + tl) * (2 * DD));

        #pragma unroll
        for (int pass = 0; pass < 4; ++pass) {
            const int dc = pass * 16 + dc0;
            float4 o = make_float4(0.f, 0.f, 0.f, 0.f);
            #pragma unroll 4
            for (int j4 = 0; j4 < WIN / 4; ++j4) {
                float4 p4 = *(const float4*)&p_t[tl][j4 * 4];
                float4 v0 = V4[(size_t)(j4 * 4 + 0) * (DD / 4) + dc];
                float4 v1 = V4[(size_t)(j4 * 4 + 1) * (DD / 4) + dc];
                float4 v2 = V4[(size_t)(j4 * 4 + 2) * (DD / 4) + dc];
                float4 v3 = V4[(size_t)(j4 * 4 + 3) * (DD / 4) + dc];
                o.x = fmaf(p4.x, v0.x, fmaf(p4.y, v1.x, fmaf(p4.z, v2.x, fmaf(p4.w, v3.x, o.x))));
                o.y = fmaf(p4.x, v0.y, fmaf(p4.y, v1.y, fmaf(p4.z, v2.y, fmaf(p4.w, v3.y, o.y))));
                o.z = fmaf(p4.x, v0.z, fmaf(p4.y, v1.z, fmaf(p4.z, v2.z, fmaf(p4.w, v3.z, o.z))));
                o.w = fmaf(p4.x, v0.w, fmaf(p4.y, v1.w, fmaf(p4.z, v2.w, fmaf(p4.w, v3.w, o.w))));
            }
            R4[dc] = o;                        // attention output
            R4[DD / 4 + dc] = Q4[dc];          // Q copy
        }
    }
}

extern "C" void kernel_launch(void* const* d_in, const int* in_sizes, int n_in,
                              void* d_out, int out_size, void* d_ws, size_t ws_size,
                              hipStream_t stream) {
    const float* Q = (const float*)d_in[0];
    const float* K = (const float*)d_in[1];
    const float* V = (const float*)d_in[2];
    const int* prev = (const int*)d_in[3];
    float* out = (float*)d_out;

    // 1024 attention blocks (even) + 1024 zero-fill blocks (odd).
    attn_fused<<<2 * (BB * TT / TBLK), 256, 0, stream>>>(Q, K, V, prev, out);
}

// Round 4
// 178.167 us; speedup vs baseline: 1.6948x; 1.6948x over previous
//
#include <hip/hip_runtime.h>

// B=16, T=1024, N=1024, D=256, WIN=64
// outputs (flat): R (B,T,2D) = [A@V, Q]   : 8388608 f32
//                 alignments (B,N,T) = A^T: 16777216 f32
//                 max_att (B,T)           : 16384 f32
//
// v4: kill the K-scatter. The window rows [prev, prev+64) are CONTIGUOUS in
// K (64 KB), so stage them into LDS with perfectly linear coalesced float4
// loads; QK then reads K from LDS (rows padded to 260 floats -> lane-stride
// 260 dwords == 4 mod 32 == same bank distribution as the optimal linear
// b128 pattern). One kernel, no memset, full alignment strips per block.

#define BB 16
#define TT 1024
#define NN 1024
#define DD 256
#define WIN 64
#define TBLK 32          // queries per block
#define NTHREADS 512     // 8 waves

#define R_ELEMS   (16u*1024u*512u)        // 8388608
#define ALN_ELEMS (16u*1024u*1024u)       // 16777216

#define KS_STRIDE 260    // 256 + 4 pad floats per K row

__global__ __launch_bounds__(NTHREADS, 4) void attn_v4(
    const float* __restrict__ Q, const float* __restrict__ K,
    const float* __restrict__ V, const int* __restrict__ prev_in,
    float* __restrict__ out)
{
    __shared__ float ks[WIN * KS_STRIDE];    // 66560 B: K window, padded rows
    __shared__ float p_lds[TBLK][WIN + 4];   // 8704 B: probabilities [t][j]

    float* Rout   = out;
    float* aligns = out + R_ELEMS;
    float* maxatt = out + R_ELEMS + ALN_ELEMS;

    const int tid  = threadIdx.x;
    const int lane = tid & 63;
    const int w    = tid >> 6;            // wave 0..7
    const int b    = blockIdx.x >> 5;     // 32 blocks per batch
    const int t0   = (blockIdx.x & 31) * TBLK;
    const int prev = prev_in[b];

    // ---- Stage K window: 64 KB contiguous source, linear coalesced. ----
    {
        const float4* Ksrc = (const float4*)(K + ((size_t)b * NN + prev) * DD);
        #pragma unroll
        for (int k = 0; k < 8; ++k) {
            int t4 = tid + k * NTHREADS;       // 0..4095 float4 chunks
            int r  = t4 >> 6;                  // K row
            int c  = t4 & 63;                  // chunk in row
            float4 v = Ksrc[t4];
            *(float4*)&ks[r * KS_STRIDE + c * 4] = v;
        }
    }
    __syncthreads();

    // ---- QK^T: wave w -> queries t0+w*4+{0..3}; lane = window col j. ----
    const float* qb = Q + ((size_t)b * TT + t0 + w * 4) * DD;
    float acc[4] = {0.f, 0.f, 0.f, 0.f};
    #pragma unroll 4
    for (int d4 = 0; d4 < DD / 4; ++d4) {
        float4 kk = *(const float4*)&ks[lane * KS_STRIDE + d4 * 4];
        #pragma unroll
        for (int t = 0; t < 4; ++t) {
            float4 q = ((const float4*)(qb + t * DD))[d4];  // wave-uniform
            acc[t] = fmaf(q.x, kk.x, fmaf(q.y, kk.y, fmaf(q.z, kk.z, fmaf(q.w, kk.w, acc[t]))));
        }
    }

    // ---- Softmax + argmax; p -> LDS. ----
    #pragma unroll
    for (int t = 0; t < 4; ++t) {
        float v = acc[t] * 0.0625f;           // 1/sqrt(256)

        float m = v;
        #pragma unroll
        for (int off = 32; off; off >>= 1) m = fmaxf(m, __shfl_xor(m, off));

        float e = expf(v - m);
        float s = e;
        #pragma unroll
        for (int off = 32; off; off >>= 1) s += __shfl_xor(s, off);

        p_lds[w * 4 + t][lane] = e / s;

        float av = v; int ai = lane;
        #pragma unroll
        for (int off = 32; off; off >>= 1) {
            float ov = __shfl_xor(av, off);
            int   oi = __shfl_xor(ai, off);
            if (ov > av || (ov == av && oi < ai)) { av = ov; ai = oi; }
        }
        if (lane == 0) maxatt[(size_t)b * TT + t0 + w * 4 + t] = (float)(prev + ai);
    }

    // ---- PV (wave-local: reads only this wave's p rows). lane = d-chunk. ----
    {
        const float4* V4 = (const float4*)(V + ((size_t)b * NN + prev) * DD);
        float4 o[4];
        #pragma unroll
        for (int t = 0; t < 4; ++t) o[t] = make_float4(0.f, 0.f, 0.f, 0.f);

        #pragma unroll 2
        for (int j4 = 0; j4 < WIN / 4; ++j4) {
            float4 vv0 = V4[(size_t)(j4 * 4 + 0) * (DD / 4) + lane];
            float4 vv1 = V4[(size_t)(j4 * 4 + 1) * (DD / 4) + lane];
            float4 vv2 = V4[(size_t)(j4 * 4 + 2) * (DD / 4) + lane];
            float4 vv3 = V4[(size_t)(j4 * 4 + 3) * (DD / 4) + lane];
            #pragma unroll
            for (int t = 0; t < 4; ++t) {
                float4 p4 = *(const float4*)&p_lds[w * 4 + t][j4 * 4];  // broadcast
                o[t].x = fmaf(p4.x, vv0.x, fmaf(p4.y, vv1.x, fmaf(p4.z, vv2.x, fmaf(p4.w, vv3.x, o[t].x))));
                o[t].y = fmaf(p4.x, vv0.y, fmaf(p4.y, vv1.y, fmaf(p4.z, vv2.y, fmaf(p4.w, vv3.y, o[t].y))));
                o[t].z = fmaf(p4.x, vv0.z, fmaf(p4.y, vv1.z, fmaf(p4.z, vv2.z, fmaf(p4.w, vv3.z, o[t].z))));
                o[t].w = fmaf(p4.x, vv0.w, fmaf(p4.y, vv1.w, fmaf(p4.z, vv2.w, fmaf(p4.w, vv3.w, o[t].w))));
            }
        }

        #pragma unroll
        for (int t = 0; t < 4; ++t) {
            float* Rrow = Rout + ((size_t)b * TT + t0 + w * 4 + t) * (2 * DD);
            ((float4*)Rrow)[lane] = o[t];
            float4 qv = ((const float4*)(qb + t * DD))[lane];   // coalesced
            ((float4*)(Rrow + DD))[lane] = qv;
        }
    }
    __syncthreads();

    // ---- Alignment strip: all 1024 rows x 32 cols (zeros + window p). ----
    // thread = (rgrp = tid>>3 in [0,64), cg = tid&7); 16 passes over rows.
    {
        const int rgrp = tid >> 3;
        const int cg   = tid & 7;
        float* abase = aligns + (size_t)b * NN * TT + t0 + cg * 4;
        #pragma unroll 4
        for (int pass = 0; pass < 16; ++pass) {
            int row = pass * 64 + rgrp;
            int iw  = row - prev;
            float4 v = make_float4(0.f, 0.f, 0.f, 0.f);
            if ((unsigned)iw < WIN) {
                v.x = p_lds[cg * 4 + 0][iw];
                v.y = p_lds[cg * 4 + 1][iw];
                v.z = p_lds[cg * 4 + 2][iw];
                v.w = p_lds[cg * 4 + 3][iw];
            }
            *(float4*)(abase + (size_t)row * TT) = v;   // 128B/row group, full lines
        }
    }
}

extern "C" void kernel_launch(void* const* d_in, const int* in_sizes, int n_in,
                              void* d_out, int out_size, void* d_ws, size_t ws_size,
                              hipStream_t stream) {
    const float* Q = (const float*)d_in[0];
    const float* K = (const float*)d_in[1];
    const float* V = (const float*)d_in[2];
    const int* prev = (const int*)d_in[3];
    float* out = (float*)d_out;

    // 32 blocks per batch x 16 batches = 512 blocks x 512 threads.
    attn_v4<<<BB * TT / TBLK, NTHREADS, 0, stream>>>(Q, K, V, prev, out);
}